// Round 7
// baseline (741.559 us; speedup 1.0000x reference)
//
#include <hip/hip_runtime.h>

#define B_TOT 32768
#define T_OBS 64
#define F_FUT 64
#define S_DIM 5
#define H_DIM 128
#define A_DIM 16
#define R_BLK 64
#define NTHREADS 512
#define XSTR 320      // T*S row stride of obs/target (floats)

// ---- LDS geometry (shorts) ----
#define HSTR 136      // h row stride: 272B = 68 dw ≡ 4 (mod 32) -> b128 reads at bytes-floor
#define HBUF (R_BLK * HSTR)        // 8704 shorts per h buffer
#define XPAD 38       // x row stride: 76B, 19 dw (odd) -> conflict-free-ish b64
#define XBUF (R_BLK * XPAD)        // 2432 shorts per x buffer
#define APAD 24       // adapter row stride (48B)
#define ABUF (R_BLK * APAD)        // 1536 shorts per adapter plane
#define RT_H (16 * HSTR)           // 2176: row-tile stride in h buffer
#define RT_X (16 * XPAD)           // 608
#define RT_A (16 * APAD)           // 384

#define LOG2E 1.4426950408889634f
#define L2E2  2.8853900817779268f

typedef __attribute__((ext_vector_type(8))) short short8;
typedef __attribute__((ext_vector_type(4))) float f32x4;

union U8 { short8 v; unsigned int u[4]; unsigned short s[8]; };

#if __has_builtin(__builtin_amdgcn_exp2f)
#define EXP2(x) __builtin_amdgcn_exp2f(x)
#else
#define EXP2(x) exp2f(x)
#endif

__device__ __forceinline__ unsigned short f2bf(float f) {
  unsigned int u = __float_as_uint(f);
  u += 0x7FFFu + ((u >> 16) & 1u);   // RNE
  return (unsigned short)(u >> 16);
}

__device__ __forceinline__ unsigned cvtpk(float a, float b) {
  unsigned r;
  asm("v_cvt_pk_bf16_f32 %0, %1, %2" : "=v"(r) : "v"(a), "v"(b));
  return r;
}

__device__ __forceinline__ f32x4 MFMA(short8 a, short8 b, f32x4 c) {
  return __builtin_amdgcn_mfma_f32_16x16x32_bf16(a, b, c, 0, 0, 0);
}

// h LDS: fragment-packed per row, NO rotation: k = 32ks+16h+4g+j at short 32ks+8g+4h+j.
// All offsets below are compile-time constants folded into ds_read/ds_write imms.
__device__ __forceinline__ short8 h_rd(const unsigned short* p, int rt, int ks) {
  return *(const short8*)(p + rt * RT_H + ks * 32);
}

// A-fragment loader: rows g0+lr of row-major W[.][ld], scaled; k = 32ks+16(i>>2)+4lg+(i&3)
__device__ __forceinline__ short8 load_w(const float* __restrict__ W, int ld,
                                         int g0, int gmax, int kmax, int ks,
                                         int lr, int lg, float scale) {
  U8 a;
  const int g = g0 + lr;
  #pragma unroll
  for (int i = 0; i < 8; ++i) {
    int k = 32 * ks + 16 * (i >> 2) + 4 * lg + (i & 3);
    float v = (g < gmax && k < kmax) ? W[g * ld + k] * scale : 0.0f;
    a.s[i] = f2bf(v);
  }
  return a.v;
}

__device__ __forceinline__ void setup_weights(
    const float* __restrict__ Wih, const float* __restrict__ Whh,
    const float* __restrict__ bih, const float* __restrict__ bhh,
    short8 (&fh)[3][4], short8 (&fx)[3],
    f32x4& brz0, f32x4& brz1, f32x4& bnh, f32x4& bnx,
    int w, int lr, int lg)
{
  #pragma unroll
  for (int t = 0; t < 3; ++t) {
    const float sc = (t == 2) ? L2E2 : LOG2E;
    #pragma unroll
    for (int ks = 0; ks < 4; ++ks)
      fh[t][ks] = load_w(Whh, H_DIM, t * H_DIM + 16 * w, 384, H_DIM, ks, lr, lg, sc);
    fx[t] = load_w(Wih, S_DIM, t * H_DIM + 16 * w, 384, S_DIM, 0, lr, lg, sc);
  }
  #pragma unroll
  for (int i = 0; i < 4; ++i) {
    int g = 16 * w + 4 * lg + i;
    brz0[i] = (bih[g] + bhh[g]) * LOG2E;
    brz1[i] = (bih[H_DIM + g] + bhh[H_DIM + g]) * LOG2E;
    bnh[i]  = bhh[2 * H_DIM + g] * L2E2;
    bnx[i]  = bih[2 * H_DIM + g] * L2E2;
  }
}

// Phase 1: LDS reads + 15-MFMA cluster (setprio-wrapped)
__device__ __forceinline__ void mfma_rt(
    const unsigned short* __restrict__ ph, const unsigned short* __restrict__ px,
    int rt,
    const short8 (&fh)[3][4], const short8 (&fx)[3],
    const f32x4& brz0, const f32x4& brz1, const f32x4& bnh, const f32x4& bnx,
    f32x4& aR, f32x4& aZ, f32x4& aN, f32x4& aX)
{
  U8 bx;
  { uint2 t = *(const uint2*)(px + rt * RT_X);
    bx.u[0] = t.x; bx.u[1] = t.y; bx.u[2] = 0u; bx.u[3] = 0u; }
  short8 bh0 = h_rd(ph, rt, 0);
  short8 bh1 = h_rd(ph, rt, 1);
  short8 bh2 = h_rd(ph, rt, 2);
  short8 bh3 = h_rd(ph, rt, 3);
  __builtin_amdgcn_s_setprio(1);
  aR = MFMA(fh[0][0], bh0, brz0);
  aR = MFMA(fh[0][1], bh1, aR);
  aR = MFMA(fh[0][2], bh2, aR);
  aR = MFMA(fh[0][3], bh3, aR);
  aR = MFMA(fx[0], bx.v, aR);
  aZ = MFMA(fh[1][0], bh0, brz1);
  aZ = MFMA(fh[1][1], bh1, aZ);
  aZ = MFMA(fh[1][2], bh2, aZ);
  aZ = MFMA(fh[1][3], bh3, aZ);
  aZ = MFMA(fx[1], bx.v, aZ);
  aN = MFMA(fh[2][0], bh0, bnh);
  aN = MFMA(fh[2][1], bh1, aN);
  aN = MFMA(fh[2][2], bh2, aN);
  aN = MFMA(fh[2][3], bh3, aN);
  aX = MFMA(fx[2], bx.v, bnx);
  __builtin_amdgcn_s_setprio(0);
}

// Phase 2: activations + pack + LDS write (imm-offset write)
__device__ __forceinline__ void act_rt(
    const f32x4& aR, const f32x4& aZ, const f32x4& aN, const f32x4& aX,
    float (&hreg)[4], unsigned short* __restrict__ pw, int rt)
{
  float hv[4];
  #pragma unroll
  for (int i = 0; i < 4; ++i) {
    float r = __builtin_amdgcn_rcpf(1.0f + EXP2(-aR[i]));
    float z = __builtin_amdgcn_rcpf(1.0f + EXP2(-aZ[i]));
    float v = fmaf(r, aN[i], aX[i]);
    float q = __builtin_amdgcn_rcpf(1.0f + EXP2(-v));
    float n = fmaf(2.0f, q, -1.0f);          // tanh
    float h = fmaf(z, hreg[i] - n, n);
    hreg[i] = h; hv[i] = h;
  }
  *(uint2*)(pw + rt * RT_H) = make_uint2(cvtpk(hv[0], hv[1]), cvtpk(hv[2], hv[3]));
}

// Software-pipelined GRU step: MFMA(rt) overlaps act(rt-1)
__device__ __forceinline__ void gru_step(
    const unsigned short* __restrict__ ph, const unsigned short* __restrict__ px,
    unsigned short* __restrict__ pw,
    const short8 (&fh)[3][4], const short8 (&fx)[3],
    const f32x4& brz0, const f32x4& brz1, const f32x4& bnh, const f32x4& bnx,
    float (&h_reg)[4][4])
{
  f32x4 aR0, aZ0, aN0, aX0, aR1, aZ1, aN1, aX1;
  mfma_rt(ph, px, 0, fh, fx, brz0, brz1, bnh, bnx, aR0, aZ0, aN0, aX0);
  mfma_rt(ph, px, 1, fh, fx, brz0, brz1, bnh, bnx, aR1, aZ1, aN1, aX1);
  act_rt(aR0, aZ0, aN0, aX0, h_reg[0], pw, 0);
  mfma_rt(ph, px, 2, fh, fx, brz0, brz1, bnh, bnx, aR0, aZ0, aN0, aX0);
  act_rt(aR1, aZ1, aN1, aX1, h_reg[1], pw, 1);
  mfma_rt(ph, px, 3, fh, fx, brz0, brz1, bnh, bnx, aR1, aZ1, aN1, aX1);
  act_rt(aR0, aZ0, aN0, aX0, h_reg[2], pw, 2);
  act_rt(aR1, aZ1, aN1, aX1, h_reg[3], pw, 3);
}

__global__ __launch_bounds__(NTHREADS, 2) void trace_gru_kernel(
    const float* __restrict__ obs, const float* __restrict__ target,
    const int* __restrict__ ids,
    const float* __restrict__ eWih, const float* __restrict__ eWhh,
    const float* __restrict__ ebih, const float* __restrict__ ebhh,
    const float* __restrict__ cWih, const float* __restrict__ cWhh,
    const float* __restrict__ cbih, const float* __restrict__ cbhh,
    const float* __restrict__ headW, const float* __restrict__ headb,
    const float* __restrict__ ppW1, const float* __restrict__ ppb1,
    const float* __restrict__ ppW2, const float* __restrict__ ppb2,
    const float* __restrict__ pkW1, const float* __restrict__ pkb1,
    const float* __restrict__ pkW2, const float* __restrict__ pkb2,
    float* __restrict__ out)
{
  __shared__ __align__(16) unsigned short h_lds[2 * HBUF];
  __shared__ __align__(16) unsigned short x_lds[2 * XBUF];
  __shared__ __align__(16) unsigned short a_lds[2 * ABUF];
  __shared__ __align__(16) unsigned short wd_lds[12 * 512];

  const int tid = threadIdx.x;
  const int lane = tid & 63;
  const int w = tid >> 6;
  const int lr = lane & 15;
  const int lg = lane >> 4;
  const int row0 = blockIdx.x * R_BLK;

  // ---- precomputed per-lane LDS base pointers (all later accesses are +imm) ----
  const unsigned short* hr0 = &h_lds[0] + lr * HSTR + lg * 8;        // h read, buf0
  const unsigned short* hr1 = hr0 + HBUF;                            // h read, buf1
  unsigned short* hw0 = &h_lds[0] + lr * HSTR +
                        (4 * (w >> 1) + lg) * 8 + (w & 1) * 4;       // h write, buf0
  unsigned short* hw1 = hw0 + HBUF;
  const unsigned short* xr0 = &x_lds[0] + lr * XPAD + 4 * lg;        // x read, buf0
  const unsigned short* xr1 = xr0 + XBUF;
  // adapter GEMM1 h-read base (row-tile w>>1 of buf1), hoisted wave-uniform part
  const unsigned short* ha = hr1 + (w >> 1) * RT_H;
  // head h-read base (row-tile w of buf0)
  const unsigned short* hh = hr0 + w * RT_H;
  // adapter a_lds write/read bases
  unsigned short* aw = &a_lds[0] + (w & 1) * ABUF + (w >> 1) * RT_A + lr * APAD + 4 * lg;
  const unsigned short* ar = &a_lds[0] + lr * APAD + 4 * lg;
  // wd bases
  const unsigned short* wda = &wd_lds[0] + (w & 1) * 2048 + lane * 8;
  const unsigned short* wdh = &wd_lds[0] + 4096 + lane * 8;

  {
    unsigned int* p = (unsigned int*)&h_lds[0];
    for (int i = tid; i < HBUF / 2; i += NTHREADS) p[i] = 0u;   // zero buf0
    unsigned int* q = (unsigned int*)&x_lds[0];
    for (int i = tid; i < XBUF; i += NTHREADS) q[i] = 0u;       // zero both x buffers
  }

  const bool xa = (tid < R_BLK * S_DIM);
  const int sx_row = tid / 5;
  const int sx_s = tid - 5 * sx_row;
  unsigned short* xs = &x_lds[0] + sx_row * XPAD + sx_s;
  const float* pobs = obs + (size_t)(row0 + sx_row) * XSTR + sx_s;
  const float* ptgt = target + (size_t)(row0 + sx_row) * XSTR + sx_s;
  float xe = 0.f;

  float pmf[4], kmf[4];
  #pragma unroll
  for (int rt = 0; rt < 4; ++rt) {
    int id = ids[row0 + rt * 16 + lr];
    pmf[rt] = (id == 0) ? 1.0f : 0.0f;
    kmf[rt] = (id == 1) ? 1.0f : 0.0f;
  }

  short8 fh[3][4], fx[3];
  f32x4 brz0, brz1, bnh, bnx;
  setup_weights(eWih, eWhh, ebih, ebhh, fh, fx, brz0, brz1, bnh, bnx, w, lr, lg);

  float h_reg[4][4];
  #pragma unroll
  for (int rt = 0; rt < 4; ++rt)
    #pragma unroll
    for (int i = 0; i < 4; ++i) h_reg[rt][i] = 0.0f;

  __syncthreads();
  if (xa) {
    xs[0] = f2bf(pobs[0]);    // v = 0 into x buf0
    xe = pobs[5];             // v = 1
  }
  __syncthreads();

  // ---------------- encoder: 64 GRU steps, 2-step unrolled ----------------
  for (int it = 0; it < T_OBS / 2; ++it) {
    const int u = 2 * it;
    // even step (parity 0): read h0/x0, write h1
    float xn = 0.f;
    if (xa) {
      int v = u + 2;
      xn = (v < 64) ? pobs[v * 5] : pobs[315];        // v=64 -> obs[63]
    }
    gru_step(hr0, xr0, hw1, fh, fx, brz0, brz1, bnh, bnx, h_reg);
    if (xa) xs[XBUF] = f2bf(xe);
    __syncthreads();
    xe = xn;
    // odd step (parity 1): read h1/x1, write h0
    xn = 0.f;
    if (xa) {
      int v = u + 3;
      xn = (v < 64) ? pobs[v * 5] : ptgt[0];          // v=65 -> target[0]
    }
    gru_step(hr1, xr1, hw0, fh, fx, brz0, brz1, bnh, bnx, h_reg);
    if (xa) xs[0] = f2bf(xe);
    __syncthreads();
    xe = xn;
  }

  // ---------------- decoder setup ----------------
  setup_weights(cWih, cWhh, cbih, cbhh, fh, fx, brz0, brz1, bnh, bnx, w, lr, lg);
  short8 fW2[2];
  fW2[0] = load_w(ppW2, A_DIM, 16 * w, H_DIM, A_DIM, 0, lr, lg, 1.0f);
  fW2[1] = load_w(pkW2, A_DIM, 16 * w, H_DIM, A_DIM, 0, lr, lg, 1.0f);
  f32x4 b1v, b2v0, b2v1, hbv;
  {
    const float* b1p = (w & 1) ? pkb1 : ppb1;
    #pragma unroll
    for (int i = 0; i < 4; ++i) {
      b1v[i]  = b1p[4 * lg + i];
      b2v0[i] = ppb2[16 * w + 4 * lg + i];
      b2v1[i] = pkb2[16 * w + 4 * lg + i];
      int s = 4 * lg + i;
      hbv[i] = (s < S_DIM) ? headb[s] : 0.0f;
    }
  }
  for (int f = w; f < 12; f += 8) {
    short8 v;
    if (f < 8) {
      const float* W1 = (f >> 2) ? pkW1 : ppW1;
      v = load_w(W1, H_DIM, 0, A_DIM, H_DIM, f & 3, lr, lg, 1.0f);
    } else {
      v = load_w(headW, H_DIM, 0, S_DIM, H_DIM, f - 8, lr, lg, 1.0f);
    }
    *(short8*)&wd_lds[f * 512 + lane * 8] = v;
  }
  float* op_base = out + (size_t)(row0 + w * 16 + lr) * (F_FUT * S_DIM);
  __syncthreads();

  // ---------------- decoder: 64 steps (GRU + adapter + head) ----------------
  for (int d = 0; d < F_FUT; ++d) {
    float xn = 0.f;
    if (xa) xn = (d < 63) ? ptgt[(d + 1) * 5] : ptgt[315];
    // read h buf0 + x parity, write h buf1
    gru_step(hr0, (d & 1) ? xr1 : xr0, hw1, fh, fx, brz0, brz1, bnh, bnx, h_reg);
    __syncthreads();  // BAR1: h_gru visible

    {   // adapter GEMM1: wave w -> adapter (w&1), row-tile (w>>1)
      short8 b0 = *(const short8*)(ha + 0);
      f32x4 acc = MFMA(*(const short8*)(wda + 0 * 512), b0, b1v);
      #pragma unroll
      for (int ks = 1; ks < 4; ++ks) {
        short8 bh = *(const short8*)(ha + ks * 32);
        acc = MFMA(*(const short8*)(wda + ks * 512), bh, acc);
      }
      *(uint2*)aw = make_uint2(cvtpk(fmaxf(acc[0], 0.f), fmaxf(acc[1], 0.f)),
                               cvtpk(fmaxf(acc[2], 0.f), fmaxf(acc[3], 0.f)));
    }
    __syncthreads();  // BAR2: a visible

    #pragma unroll
    for (int rt = 0; rt < 4; ++rt) {  // adapter GEMM2 + combine
      U8 a0, a1;
      { uint2 t = *(const uint2*)(ar + rt * RT_A);
        a0.u[0] = t.x; a0.u[1] = t.y; a0.u[2] = 0u; a0.u[3] = 0u; }
      { uint2 t = *(const uint2*)(ar + ABUF + rt * RT_A);
        a1.u[0] = t.x; a1.u[1] = t.y; a1.u[2] = 0u; a1.u[3] = 0u; }
      f32x4 d0 = MFMA(fW2[0], a0.v, b2v0);
      f32x4 d1 = MFMA(fW2[1], a1.v, b2v1);
      float hv[4];
      #pragma unroll
      for (int i = 0; i < 4; ++i) {
        float h = h_reg[rt][i] + pmf[rt] * d0[i] + kmf[rt] * d1[i];
        h_reg[rt][i] = h; hv[i] = h;
      }
      *(uint2*)(hw0 + rt * RT_H) =
          make_uint2(cvtpk(hv[0], hv[1]), cvtpk(hv[2], hv[3]));
    }
    if (xa && d < 63) xs[((d + 1) & 1) * XBUF] = f2bf(xe);
    __syncthreads();  // BAR3: h_final visible

    if (w < 4) {  // head: wave w handles row-tile w
      short8 b0 = *(const short8*)(hh + 0);
      f32x4 acc = MFMA(*(const short8*)(wdh + 0 * 512), b0, hbv);
      #pragma unroll
      for (int ks = 1; ks < 4; ++ks) {
        short8 bh = *(const short8*)(hh + ks * 32);
        acc = MFMA(*(const short8*)(wdh + ks * 512), bh, acc);
      }
      float* op = op_base + d * S_DIM;
      if (lg == 0) { op[0] = acc[0]; op[1] = acc[1]; op[2] = acc[2]; op[3] = acc[3]; }
      else if (lg == 1) { op[4] = acc[0]; }
    }
    xe = xn;
  }
}

extern "C" void kernel_launch(void* const* d_in, const int* in_sizes, int n_in,
                              void* d_out, int out_size, void* d_ws, size_t ws_size,
                              hipStream_t stream) {
  (void)in_sizes; (void)n_in; (void)out_size; (void)d_ws; (void)ws_size;
  const float* obs    = (const float*)d_in[0];
  const float* target = (const float*)d_in[1];
  const int*   ids    = (const int*)d_in[2];
  const float* eWih = (const float*)d_in[3];
  const float* eWhh = (const float*)d_in[4];
  const float* ebih = (const float*)d_in[5];
  const float* ebhh = (const float*)d_in[6];
  const float* cWih = (const float*)d_in[7];
  const float* cWhh = (const float*)d_in[8];
  const float* cbih = (const float*)d_in[9];
  const float* cbhh = (const float*)d_in[10];
  const float* headW = (const float*)d_in[11];
  const float* headb = (const float*)d_in[12];
  const float* ppW1 = (const float*)d_in[13];
  const float* ppb1 = (const float*)d_in[14];
  const float* ppW2 = (const float*)d_in[15];
  const float* ppb2 = (const float*)d_in[16];
  const float* pkW1 = (const float*)d_in[17];
  const float* pkb1 = (const float*)d_in[18];
  const float* pkW2 = (const float*)d_in[19];
  const float* pkb2 = (const float*)d_in[20];

  dim3 grid(B_TOT / R_BLK), block(NTHREADS);
  trace_gru_kernel<<<grid, block, 0, stream>>>(
      obs, target, ids,
      eWih, eWhh, ebih, ebhh,
      cWih, cWhh, cbih, cbhh,
      headW, headb,
      ppW1, ppb1, ppW2, ppb2,
      pkW1, pkb1, pkW2, pkb2,
      (float*)d_out);
}

// Round 8
// 731.230 us; speedup vs baseline: 1.0141x; 1.0141x over previous
//
#include <hip/hip_runtime.h>

#define B_TOT 32768
#define T_OBS 64
#define F_FUT 64
#define S_DIM 5
#define H_DIM 128
#define A_DIM 16
#define R_BLK 64
#define NTHREADS 512
#define XSTR 320     // T*S row stride of obs/target (floats)
#define HSTR 128     // h LDS row stride (shorts): fragment-packed, rotated 16B chunks
#define XPAD 36      // x LDS row stride (shorts)

#define LOG2E 1.4426950408889634f
#define L2E2  2.8853900817779268f

typedef __attribute__((ext_vector_type(8))) short short8;
typedef __attribute__((ext_vector_type(4))) float f32x4;

union U8 { short8 v; unsigned int u[4]; unsigned short s[8]; };

#if __has_builtin(__builtin_amdgcn_exp2f)
#define EXP2(x) __builtin_amdgcn_exp2f(x)
#else
#define EXP2(x) exp2f(x)
#endif

__device__ __forceinline__ unsigned short f2bf(float f) {
  unsigned int u = __float_as_uint(f);
  u += 0x7FFFu + ((u >> 16) & 1u);   // RNE
  return (unsigned short)(u >> 16);
}

__device__ __forceinline__ unsigned cvtpk(float a, float b) {
  unsigned r;
  asm("v_cvt_pk_bf16_f32 %0, %1, %2" : "=v"(r) : "v"(a), "v"(b));
  return r;
}

__device__ __forceinline__ f32x4 MFMA(short8 a, short8 b, f32x4 c) {
  return __builtin_amdgcn_mfma_f32_16x16x32_bf16(a, b, c, 0, 0, 0);
}

// ---- h LDS layout: row stride 128 shorts, fragment-packed:
// k = 32*ks + 16*h + 4*g + j  stored at  s = 32*ks + 8*g + 4*h + j,
// 16B chunks rotated by (chunk + row) & 15 -> conflict-free b128 reads.
__device__ __forceinline__ short8 h_read(const unsigned short* base, int row, int ks, int lg) {
  return *(const short8*)(base + row * HSTR + (((4 * ks + lg + row) & 15) << 3));
}
// wave w writes gates 16w+4lg+j: chunk 4*(w>>1)+lg, half (w&1)
__device__ __forceinline__ void h_write(unsigned short* base, int row, int w, int lg,
                                        unsigned lo, unsigned hi) {
  unsigned short* p = base + row * HSTR +
                      (((4 * (w >> 1) + lg + row) & 15) << 3) + ((w & 1) << 2);
  *(uint2*)p = make_uint2(lo, hi);
}

// A-fragment loader: rows g0+lr of row-major W[.][ld], scaled; k = 32ks+16(i>>2)+4lg+(i&3)
__device__ __forceinline__ short8 load_w(const float* __restrict__ W, int ld,
                                         int g0, int gmax, int kmax, int ks,
                                         int lr, int lg, float scale) {
  U8 a;
  const int g = g0 + lr;
  #pragma unroll
  for (int i = 0; i < 8; ++i) {
    int k = 32 * ks + 16 * (i >> 2) + 4 * lg + (i & 3);
    float v = (g < gmax && k < kmax) ? W[g * ld + k] * scale : 0.0f;
    a.s[i] = f2bf(v);
  }
  return a.v;
}

__device__ __forceinline__ void setup_weights(
    const float* __restrict__ Wih, const float* __restrict__ Whh,
    const float* __restrict__ bih, const float* __restrict__ bhh,
    short8 (&fh)[3][4], short8 (&fx)[3],
    f32x4& brz0, f32x4& brz1, f32x4& bnh, f32x4& bnx,
    int w, int lr, int lg)
{
  #pragma unroll
  for (int t = 0; t < 3; ++t) {
    const float sc = (t == 2) ? L2E2 : LOG2E;
    #pragma unroll
    for (int ks = 0; ks < 4; ++ks)
      fh[t][ks] = load_w(Whh, H_DIM, t * H_DIM + 16 * w, 384, H_DIM, ks, lr, lg, sc);
    fx[t] = load_w(Wih, S_DIM, t * H_DIM + 16 * w, 384, S_DIM, 0, lr, lg, sc);
  }
  #pragma unroll
  for (int i = 0; i < 4; ++i) {
    int g = 16 * w + 4 * lg + i;
    brz0[i] = (bih[g] + bhh[g]) * LOG2E;
    brz1[i] = (bih[H_DIM + g] + bhh[H_DIM + g]) * LOG2E;
    bnh[i]  = bhh[2 * H_DIM + g] * L2E2;
    bnx[i]  = bih[2 * H_DIM + g] * L2E2;
  }
}

// Phase 1: LDS reads + 15-MFMA cluster (setprio-wrapped)
__device__ __forceinline__ void mfma_rt(
    const unsigned short* __restrict__ hb, const unsigned short* __restrict__ xb,
    int row, int lg,
    const short8 (&fh)[3][4], const short8 (&fx)[3],
    const f32x4& brz0, const f32x4& brz1, const f32x4& bnh, const f32x4& bnx,
    f32x4& aR, f32x4& aZ, f32x4& aN, f32x4& aX)
{
  U8 bx;
  { uint2 t = *(const uint2*)(xb + row * XPAD + 4 * lg);
    bx.u[0] = t.x; bx.u[1] = t.y; bx.u[2] = 0u; bx.u[3] = 0u; }
  short8 bh0 = h_read(hb, row, 0, lg);
  short8 bh1 = h_read(hb, row, 1, lg);
  short8 bh2 = h_read(hb, row, 2, lg);
  short8 bh3 = h_read(hb, row, 3, lg);
  __builtin_amdgcn_s_setprio(1);
  aR = MFMA(fh[0][0], bh0, brz0);
  aR = MFMA(fh[0][1], bh1, aR);
  aR = MFMA(fh[0][2], bh2, aR);
  aR = MFMA(fh[0][3], bh3, aR);
  aR = MFMA(fx[0], bx.v, aR);
  aZ = MFMA(fh[1][0], bh0, brz1);
  aZ = MFMA(fh[1][1], bh1, aZ);
  aZ = MFMA(fh[1][2], bh2, aZ);
  aZ = MFMA(fh[1][3], bh3, aZ);
  aZ = MFMA(fx[1], bx.v, aZ);
  aN = MFMA(fh[2][0], bh0, bnh);
  aN = MFMA(fh[2][1], bh1, aN);
  aN = MFMA(fh[2][2], bh2, aN);
  aN = MFMA(fh[2][3], bh3, aN);
  aX = MFMA(fx[2], bx.v, bnx);
  __builtin_amdgcn_s_setprio(0);
}

// Phase 2: activations + pack + LDS write
__device__ __forceinline__ void act_rt(
    const f32x4& aR, const f32x4& aZ, const f32x4& aN, const f32x4& aX,
    float (&hreg)[4], unsigned short* __restrict__ hd,
    int row, int w, int lg)
{
  float hv[4];
  #pragma unroll
  for (int i = 0; i < 4; ++i) {
    float r = __builtin_amdgcn_rcpf(1.0f + EXP2(-aR[i]));
    float z = __builtin_amdgcn_rcpf(1.0f + EXP2(-aZ[i]));
    float v = fmaf(r, aN[i], aX[i]);
    float q = __builtin_amdgcn_rcpf(1.0f + EXP2(-v));
    float n = fmaf(2.0f, q, -1.0f);          // tanh
    float h = fmaf(z, hreg[i] - n, n);
    hreg[i] = h; hv[i] = h;
  }
  h_write(hd, row, w, lg, cvtpk(hv[0], hv[1]), cvtpk(hv[2], hv[3]));
}

// Software-pipelined GRU step: MFMA(rt) overlaps act(rt-1)
__device__ __forceinline__ void gru_step(
    const unsigned short* __restrict__ hb, const unsigned short* __restrict__ xb,
    unsigned short* __restrict__ hd,
    const short8 (&fh)[3][4], const short8 (&fx)[3],
    const f32x4& brz0, const f32x4& brz1, const f32x4& bnh, const f32x4& bnx,
    float (&h_reg)[4][4], int w, int lr, int lg)
{
  f32x4 aR0, aZ0, aN0, aX0, aR1, aZ1, aN1, aX1;
  mfma_rt(hb, xb, 0 * 16 + lr, lg, fh, fx, brz0, brz1, bnh, bnx, aR0, aZ0, aN0, aX0);
  mfma_rt(hb, xb, 1 * 16 + lr, lg, fh, fx, brz0, brz1, bnh, bnx, aR1, aZ1, aN1, aX1);
  act_rt(aR0, aZ0, aN0, aX0, h_reg[0], hd, 0 * 16 + lr, w, lg);
  mfma_rt(hb, xb, 2 * 16 + lr, lg, fh, fx, brz0, brz1, bnh, bnx, aR0, aZ0, aN0, aX0);
  act_rt(aR1, aZ1, aN1, aX1, h_reg[1], hd, 1 * 16 + lr, w, lg);
  mfma_rt(hb, xb, 3 * 16 + lr, lg, fh, fx, brz0, brz1, bnh, bnx, aR1, aZ1, aN1, aX1);
  act_rt(aR0, aZ0, aN0, aX0, h_reg[2], hd, 2 * 16 + lr, w, lg);
  act_rt(aR1, aZ1, aN1, aX1, h_reg[3], hd, 3 * 16 + lr, w, lg);
}

__global__ __launch_bounds__(NTHREADS, 2) void trace_gru_kernel(
    const float* __restrict__ obs, const float* __restrict__ target,
    const int* __restrict__ ids,
    const float* __restrict__ eWih, const float* __restrict__ eWhh,
    const float* __restrict__ ebih, const float* __restrict__ ebhh,
    const float* __restrict__ cWih, const float* __restrict__ cWhh,
    const float* __restrict__ cbih, const float* __restrict__ cbhh,
    const float* __restrict__ headW, const float* __restrict__ headb,
    const float* __restrict__ ppW1, const float* __restrict__ ppb1,
    const float* __restrict__ ppW2, const float* __restrict__ ppb2,
    const float* __restrict__ pkW1, const float* __restrict__ pkb1,
    const float* __restrict__ pkW2, const float* __restrict__ pkb2,
    float* __restrict__ out)
{
  __shared__ __align__(16) unsigned short h_lds[2][R_BLK * HSTR];
  __shared__ __align__(16) unsigned short x_lds[2][R_BLK * XPAD];
  __shared__ __align__(16) unsigned short wd_lds[12 * 64 * 8];

  const int tid = threadIdx.x;
  const int lane = tid & 63;
  const int w = tid >> 6;
  const int lr = lane & 15;
  const int lg = lane >> 4;
  const int row0 = blockIdx.x * R_BLK;

  {
    unsigned int* p = (unsigned int*)&h_lds[0][0];
    for (int i = tid; i < R_BLK * HSTR / 2; i += NTHREADS) p[i] = 0u;
    unsigned int* q = (unsigned int*)&x_lds[0][0];
    for (int i = tid; i < 2 * R_BLK * XPAD / 2; i += NTHREADS) q[i] = 0u;
  }

  const bool xa = (tid < R_BLK * S_DIM);
  const int sx_row = tid / 5;
  const int sx_s = tid - 5 * sx_row;
  const float* pobs = obs + (size_t)(row0 + sx_row) * XSTR + sx_s;
  const float* ptgt = target + (size_t)(row0 + sx_row) * XSTR + sx_s;
  float xe = 0.f;

  float pmf[4], kmf[4];
  #pragma unroll
  for (int rt = 0; rt < 4; ++rt) {
    int id = ids[row0 + rt * 16 + lr];
    pmf[rt] = (id == 0) ? 1.0f : 0.0f;
    kmf[rt] = (id == 1) ? 1.0f : 0.0f;
  }

  short8 fh[3][4], fx[3];
  f32x4 brz0, brz1, bnh, bnx;
  setup_weights(eWih, eWhh, ebih, ebhh, fh, fx, brz0, brz1, bnh, bnx, w, lr, lg);

  float h_reg[4][4];
  #pragma unroll
  for (int rt = 0; rt < 4; ++rt)
    #pragma unroll
    for (int i = 0; i < 4; ++i) h_reg[rt][i] = 0.0f;

  __syncthreads();
  if (xa) {
    x_lds[0][sx_row * XPAD + sx_s] = f2bf(pobs[0]);   // v = 0
    xe = pobs[5];                                     // v = 1
  }
  __syncthreads();

  // ---------------- encoder: 64 GRU steps, 2-step unrolled ----------------
  for (int it = 0; it < T_OBS / 2; ++it) {
    const int u = 2 * it;
    // even step (parity 0)
    float xn = 0.f;
    if (xa) {
      int v = u + 2;
      xn = (v < 64) ? pobs[v * 5] : pobs[315];        // v=64 -> obs[63]
    }
    gru_step(&h_lds[0][0], &x_lds[0][0], &h_lds[1][0],
             fh, fx, brz0, brz1, bnh, bnx, h_reg, w, lr, lg);
    if (xa) x_lds[1][sx_row * XPAD + sx_s] = f2bf(xe);
    __syncthreads();
    xe = xn;
    // odd step (parity 1)
    xn = 0.f;
    if (xa) {
      int v = u + 3;
      xn = (v < 64) ? pobs[v * 5] : ptgt[0];          // v=65 -> target[0]
    }
    gru_step(&h_lds[1][0], &x_lds[1][0], &h_lds[0][0],
             fh, fx, brz0, brz1, bnh, bnx, h_reg, w, lr, lg);
    if (xa) x_lds[0][sx_row * XPAD + sx_s] = f2bf(xe);
    __syncthreads();
    xe = xn;
  }

  // ---------------- decoder setup ----------------
  setup_weights(cWih, cWhh, cbih, cbhh, fh, fx, brz0, brz1, bnh, bnx, w, lr, lg);
  short8 fW2[2];
  fW2[0] = load_w(ppW2, A_DIM, 16 * w, H_DIM, A_DIM, 0, lr, lg, 1.0f);
  fW2[1] = load_w(pkW2, A_DIM, 16 * w, H_DIM, A_DIM, 0, lr, lg, 1.0f);
  f32x4 b1v0, b1v1, b2v0, b2v1, hbv;
  #pragma unroll
  for (int i = 0; i < 4; ++i) {
    b1v0[i] = ppb1[4 * lg + i];
    b1v1[i] = pkb1[4 * lg + i];
    b2v0[i] = ppb2[16 * w + 4 * lg + i];
    b2v1[i] = pkb2[16 * w + 4 * lg + i];
    int s = 4 * lg + i;
    hbv[i] = (s < S_DIM) ? headb[s] : 0.0f;
  }
  for (int f = w; f < 12; f += 8) {
    short8 v;
    if (f < 8) {
      const float* W1 = (f >> 2) ? pkW1 : ppW1;
      v = load_w(W1, H_DIM, 0, A_DIM, H_DIM, f & 3, lr, lg, 1.0f);
    } else {
      v = load_w(headW, H_DIM, 0, S_DIM, H_DIM, f - 8, lr, lg, 1.0f);
    }
    *(short8*)&wd_lds[(f * 64 + lane) * 8] = v;
  }
  __syncthreads();

  // ---------------- decoder: 64 steps (GRU + fused adapter + head) ----------------
  for (int d = 0; d < F_FUT; ++d) {
    float xn = 0.f;
    if (xa) xn = (d < 63) ? ptgt[(d + 1) * 5] : ptgt[315];
    gru_step(&h_lds[0][0], &x_lds[d & 1][0], &h_lds[1][0],
             fh, fx, brz0, brz1, bnh, bnx, h_reg, w, lr, lg);
    __syncthreads();  // BAR1: h_gru (buf1) visible

    // Fused adapter: GEMM1 (redundant per wave, both adapters) -> relu ->
    // in-register B-fragment -> GEMM2 -> combine. No LDS exchange, no barrier.
    #pragma unroll
    for (int rt = 0; rt < 4; ++rt) {
      const int arow = rt * 16 + lr;
      short8 bh0 = h_read(&h_lds[1][0], arow, 0, lg);
      short8 bh1 = h_read(&h_lds[1][0], arow, 1, lg);
      short8 bh2 = h_read(&h_lds[1][0], arow, 2, lg);
      short8 bh3 = h_read(&h_lds[1][0], arow, 3, lg);
      f32x4 accP = MFMA(*(const short8*)&wd_lds[(0 * 64 + lane) * 8], bh0, b1v0);
      accP = MFMA(*(const short8*)&wd_lds[(1 * 64 + lane) * 8], bh1, accP);
      accP = MFMA(*(const short8*)&wd_lds[(2 * 64 + lane) * 8], bh2, accP);
      accP = MFMA(*(const short8*)&wd_lds[(3 * 64 + lane) * 8], bh3, accP);
      f32x4 accK = MFMA(*(const short8*)&wd_lds[(4 * 64 + lane) * 8], bh0, b1v1);
      accK = MFMA(*(const short8*)&wd_lds[(5 * 64 + lane) * 8], bh1, accK);
      accK = MFMA(*(const short8*)&wd_lds[(6 * 64 + lane) * 8], bh2, accK);
      accK = MFMA(*(const short8*)&wd_lds[(7 * 64 + lane) * 8], bh3, accK);
      // relu + bf16-pack: C-output (lane holds a[4lg+i][col=lr]) IS the GEMM2
      // B-fragment (b[k=4lg+j][col=lr], upper k-half zero).
      U8 pa, ka;
      pa.u[0] = cvtpk(fmaxf(accP[0], 0.f), fmaxf(accP[1], 0.f));
      pa.u[1] = cvtpk(fmaxf(accP[2], 0.f), fmaxf(accP[3], 0.f));
      pa.u[2] = 0u; pa.u[3] = 0u;
      ka.u[0] = cvtpk(fmaxf(accK[0], 0.f), fmaxf(accK[1], 0.f));
      ka.u[1] = cvtpk(fmaxf(accK[2], 0.f), fmaxf(accK[3], 0.f));
      ka.u[2] = 0u; ka.u[3] = 0u;
      f32x4 d0 = MFMA(fW2[0], pa.v, b2v0);
      f32x4 d1 = MFMA(fW2[1], ka.v, b2v1);
      float hv[4];
      #pragma unroll
      for (int i = 0; i < 4; ++i) {
        float h = h_reg[rt][i] + pmf[rt] * d0[i] + kmf[rt] * d1[i];
        h_reg[rt][i] = h; hv[i] = h;
      }
      h_write(&h_lds[0][0], arow, w, lg, cvtpk(hv[0], hv[1]), cvtpk(hv[2], hv[3]));
    }
    if (xa && d < 63) x_lds[(d + 1) & 1][sx_row * XPAD + sx_s] = f2bf(xe);
    __syncthreads();  // BAR2: h_final (buf0) visible

    if (w < 4) {  // head: wave w handles row-tile w (overlaps next step's gru)
      const int arow = w * 16 + lr;
      short8 b0 = h_read(&h_lds[0][0], arow, 0, lg);
      f32x4 acc = MFMA(*(const short8*)&wd_lds[((8 + 0) * 64 + lane) * 8], b0, hbv);
      #pragma unroll
      for (int ks = 1; ks < 4; ++ks) {
        short8 bh = h_read(&h_lds[0][0], arow, ks, lg);
        acc = MFMA(*(const short8*)&wd_lds[((8 + ks) * 64 + lane) * 8], bh, acc);
      }
      float* op = out + (size_t)((row0 + arow) * F_FUT + d) * S_DIM;
      if (lg == 0) { op[0] = acc[0]; op[1] = acc[1]; op[2] = acc[2]; op[3] = acc[3]; }
      else if (lg == 1) { op[4] = acc[0]; }
    }
    xe = xn;
  }
}

extern "C" void kernel_launch(void* const* d_in, const int* in_sizes, int n_in,
                              void* d_out, int out_size, void* d_ws, size_t ws_size,
                              hipStream_t stream) {
  (void)in_sizes; (void)n_in; (void)out_size; (void)d_ws; (void)ws_size;
  const float* obs    = (const float*)d_in[0];
  const float* target = (const float*)d_in[1];
  const int*   ids    = (const int*)d_in[2];
  const float* eWih = (const float*)d_in[3];
  const float* eWhh = (const float*)d_in[4];
  const float* ebih = (const float*)d_in[5];
  const float* ebhh = (const float*)d_in[6];
  const float* cWih = (const float*)d_in[7];
  const float* cWhh = (const float*)d_in[8];
  const float* cbih = (const float*)d_in[9];
  const float* cbhh = (const float*)d_in[10];
  const float* headW = (const float*)d_in[11];
  const float* headb = (const float*)d_in[12];
  const float* ppW1 = (const float*)d_in[13];
  const float* ppb1 = (const float*)d_in[14];
  const float* ppW2 = (const float*)d_in[15];
  const float* ppb2 = (const float*)d_in[16];
  const float* pkW1 = (const float*)d_in[17];
  const float* pkb1 = (const float*)d_in[18];
  const float* pkW2 = (const float*)d_in[19];
  const float* pkb2 = (const float*)d_in[20];

  dim3 grid(B_TOT / R_BLK), block(NTHREADS);
  trace_gru_kernel<<<grid, block, 0, stream>>>(
      obs, target, ids,
      eWih, eWhh, ebih, ebhh,
      cWih, cWhh, cbih, cbhh,
      headW, headb,
      ppW1, ppb1, ppW2, ppb2,
      pkW1, pkb1, pkW2, pkb2,
      (float*)d_out);
}

// Round 9
// 655.350 us; speedup vs baseline: 1.1315x; 1.1158x over previous
//
#include <hip/hip_runtime.h>

#define B_TOT 32768
#define T_OBS 64
#define F_FUT 64
#define S_DIM 5
#define H_DIM 128
#define A_DIM 16
#define R_BLK 64
#define NTHREADS 512
#define XSTR 320     // T*S row stride of obs/target (floats)
#define HSTR 128     // h LDS row stride (shorts): fragment-packed, skew-rotated 16B chunks
#define XPAD 36      // x LDS row stride (shorts)
#define APAD 24      // adapter LDS row stride (shorts)

#define LOG2E 1.4426950408889634f
#define L2E2  2.8853900817779268f

typedef __attribute__((ext_vector_type(8))) short short8;
typedef __attribute__((ext_vector_type(4))) float f32x4;

union U8 { short8 v; unsigned int u[4]; unsigned short s[8]; };

#if __has_builtin(__builtin_amdgcn_exp2f)
#define EXP2(x) __builtin_amdgcn_exp2f(x)
#else
#define EXP2(x) exp2f(x)
#endif

__device__ __forceinline__ unsigned short f2bf(float f) {
  unsigned int u = __float_as_uint(f);
  u += 0x7FFFu + ((u >> 16) & 1u);   // RNE
  return (unsigned short)(u >> 16);
}

__device__ __forceinline__ unsigned cvtpk(float a, float b) {
  unsigned r;
  asm("v_cvt_pk_bf16_f32 %0, %1, %2" : "=v"(r) : "v"(a), "v"(b));
  return r;
}

__device__ __forceinline__ f32x4 MFMA(short8 a, short8 b, f32x4 c) {
  return __builtin_amdgcn_mfma_f32_16x16x32_bf16(a, b, c, 0, 0, 0);
}

// ---- h LDS layout: row stride 128 shorts, fragment-packed:
// k = 32*ks + 16*h + 4*g + j  stored at  s = 32*ks + 8*g + 4*h + j,
// 16B chunks placed at ((slot + row + (row>>3)) & 15).
// The +(row>>3) skew breaks the lr<->lr+8 bank collision (banks = 4*chunk mod 32:
// rows 8 apart shift chunk by 8 -> same bank without the skew; with it, by 9 -> +4 banks).
__device__ __forceinline__ short8 h_read(const unsigned short* base, int row, int ks, int lg) {
  return *(const short8*)(base + row * HSTR +
                          (((4 * ks + lg + row + (row >> 3)) & 15) << 3));
}
// wave w writes gates 16w+4lg+j: slot 4*(w>>1)+lg, half (w&1)
__device__ __forceinline__ void h_write(unsigned short* base, int row, int w, int lg,
                                        unsigned lo, unsigned hi) {
  unsigned short* p = base + row * HSTR +
                      (((4 * (w >> 1) + lg + row + (row >> 3)) & 15) << 3) + ((w & 1) << 2);
  *(uint2*)p = make_uint2(lo, hi);
}

// A-fragment loader: rows g0+lr of row-major W[.][ld], scaled; k = 32ks+16(i>>2)+4lg+(i&3)
__device__ __forceinline__ short8 load_w(const float* __restrict__ W, int ld,
                                         int g0, int gmax, int kmax, int ks,
                                         int lr, int lg, float scale) {
  U8 a;
  const int g = g0 + lr;
  #pragma unroll
  for (int i = 0; i < 8; ++i) {
    int k = 32 * ks + 16 * (i >> 2) + 4 * lg + (i & 3);
    float v = (g < gmax && k < kmax) ? W[g * ld + k] * scale : 0.0f;
    a.s[i] = f2bf(v);
  }
  return a.v;
}

__device__ __forceinline__ void setup_weights(
    const float* __restrict__ Wih, const float* __restrict__ Whh,
    const float* __restrict__ bih, const float* __restrict__ bhh,
    short8 (&fh)[3][4], short8 (&fx)[3],
    f32x4& brz0, f32x4& brz1, f32x4& bnh, f32x4& bnx,
    int w, int lr, int lg)
{
  #pragma unroll
  for (int t = 0; t < 3; ++t) {
    const float sc = (t == 2) ? L2E2 : LOG2E;
    #pragma unroll
    for (int ks = 0; ks < 4; ++ks)
      fh[t][ks] = load_w(Whh, H_DIM, t * H_DIM + 16 * w, 384, H_DIM, ks, lr, lg, sc);
    fx[t] = load_w(Wih, S_DIM, t * H_DIM + 16 * w, 384, S_DIM, 0, lr, lg, sc);
  }
  #pragma unroll
  for (int i = 0; i < 4; ++i) {
    int g = 16 * w + 4 * lg + i;
    brz0[i] = (bih[g] + bhh[g]) * LOG2E;
    brz1[i] = (bih[H_DIM + g] + bhh[H_DIM + g]) * LOG2E;
    bnh[i]  = bhh[2 * H_DIM + g] * L2E2;
    bnx[i]  = bih[2 * H_DIM + g] * L2E2;
  }
}

// Phase 1: LDS reads + 15-MFMA cluster (setprio-wrapped)
__device__ __forceinline__ void mfma_rt(
    const unsigned short* __restrict__ hb, const unsigned short* __restrict__ xb,
    int row, int lg,
    const short8 (&fh)[3][4], const short8 (&fx)[3],
    const f32x4& brz0, const f32x4& brz1, const f32x4& bnh, const f32x4& bnx,
    f32x4& aR, f32x4& aZ, f32x4& aN, f32x4& aX)
{
  U8 bx;
  { uint2 t = *(const uint2*)(xb + row * XPAD + 4 * lg);
    bx.u[0] = t.x; bx.u[1] = t.y; bx.u[2] = 0u; bx.u[3] = 0u; }
  short8 bh0 = h_read(hb, row, 0, lg);
  short8 bh1 = h_read(hb, row, 1, lg);
  short8 bh2 = h_read(hb, row, 2, lg);
  short8 bh3 = h_read(hb, row, 3, lg);
  __builtin_amdgcn_s_setprio(1);
  aR = MFMA(fh[0][0], bh0, brz0);
  aR = MFMA(fh[0][1], bh1, aR);
  aR = MFMA(fh[0][2], bh2, aR);
  aR = MFMA(fh[0][3], bh3, aR);
  aR = MFMA(fx[0], bx.v, aR);
  aZ = MFMA(fh[1][0], bh0, brz1);
  aZ = MFMA(fh[1][1], bh1, aZ);
  aZ = MFMA(fh[1][2], bh2, aZ);
  aZ = MFMA(fh[1][3], bh3, aZ);
  aZ = MFMA(fx[1], bx.v, aZ);
  aN = MFMA(fh[2][0], bh0, bnh);
  aN = MFMA(fh[2][1], bh1, aN);
  aN = MFMA(fh[2][2], bh2, aN);
  aN = MFMA(fh[2][3], bh3, aN);
  aX = MFMA(fx[2], bx.v, bnx);
  __builtin_amdgcn_s_setprio(0);
}

// Phase 2: activations + pack + LDS write
__device__ __forceinline__ void act_rt(
    const f32x4& aR, const f32x4& aZ, const f32x4& aN, const f32x4& aX,
    float (&hreg)[4], unsigned short* __restrict__ hd,
    int row, int w, int lg)
{
  float hv[4];
  #pragma unroll
  for (int i = 0; i < 4; ++i) {
    float r = __builtin_amdgcn_rcpf(1.0f + EXP2(-aR[i]));
    float z = __builtin_amdgcn_rcpf(1.0f + EXP2(-aZ[i]));
    float v = fmaf(r, aN[i], aX[i]);
    float q = __builtin_amdgcn_rcpf(1.0f + EXP2(-v));
    float n = fmaf(2.0f, q, -1.0f);          // tanh
    float h = fmaf(z, hreg[i] - n, n);
    hreg[i] = h; hv[i] = h;
  }
  h_write(hd, row, w, lg, cvtpk(hv[0], hv[1]), cvtpk(hv[2], hv[3]));
}

// Software-pipelined GRU step: MFMA(rt) overlaps act(rt-1)
__device__ __forceinline__ void gru_step(
    const unsigned short* __restrict__ hb, const unsigned short* __restrict__ xb,
    unsigned short* __restrict__ hd,
    const short8 (&fh)[3][4], const short8 (&fx)[3],
    const f32x4& brz0, const f32x4& brz1, const f32x4& bnh, const f32x4& bnx,
    float (&h_reg)[4][4], int w, int lr, int lg)
{
  f32x4 aR0, aZ0, aN0, aX0, aR1, aZ1, aN1, aX1;
  mfma_rt(hb, xb, 0 * 16 + lr, lg, fh, fx, brz0, brz1, bnh, bnx, aR0, aZ0, aN0, aX0);
  mfma_rt(hb, xb, 1 * 16 + lr, lg, fh, fx, brz0, brz1, bnh, bnx, aR1, aZ1, aN1, aX1);
  act_rt(aR0, aZ0, aN0, aX0, h_reg[0], hd, 0 * 16 + lr, w, lg);
  mfma_rt(hb, xb, 2 * 16 + lr, lg, fh, fx, brz0, brz1, bnh, bnx, aR0, aZ0, aN0, aX0);
  act_rt(aR1, aZ1, aN1, aX1, h_reg[1], hd, 1 * 16 + lr, w, lg);
  mfma_rt(hb, xb, 3 * 16 + lr, lg, fh, fx, brz0, brz1, bnh, bnx, aR1, aZ1, aN1, aX1);
  act_rt(aR0, aZ0, aN0, aX0, h_reg[2], hd, 2 * 16 + lr, w, lg);
  act_rt(aR1, aZ1, aN1, aX1, h_reg[3], hd, 3 * 16 + lr, w, lg);
}

__global__ __launch_bounds__(NTHREADS, 2) void trace_gru_kernel(
    const float* __restrict__ obs, const float* __restrict__ target,
    const int* __restrict__ ids,
    const float* __restrict__ eWih, const float* __restrict__ eWhh,
    const float* __restrict__ ebih, const float* __restrict__ ebhh,
    const float* __restrict__ cWih, const float* __restrict__ cWhh,
    const float* __restrict__ cbih, const float* __restrict__ cbhh,
    const float* __restrict__ headW, const float* __restrict__ headb,
    const float* __restrict__ ppW1, const float* __restrict__ ppb1,
    const float* __restrict__ ppW2, const float* __restrict__ ppb2,
    const float* __restrict__ pkW1, const float* __restrict__ pkb1,
    const float* __restrict__ pkW2, const float* __restrict__ pkb2,
    float* __restrict__ out)
{
  __shared__ __align__(16) unsigned short h_lds[2][R_BLK * HSTR];
  __shared__ __align__(16) unsigned short x_lds[2][R_BLK * XPAD];
  __shared__ __align__(16) unsigned short a_lds[2 * R_BLK * APAD];
  __shared__ __align__(16) unsigned short wd_lds[12 * 64 * 8];

  const int tid = threadIdx.x;
  const int lane = tid & 63;
  const int w = tid >> 6;
  const int lr = lane & 15;
  const int lg = lane >> 4;
  const int row0 = blockIdx.x * R_BLK;

  {
    unsigned int* p = (unsigned int*)&h_lds[0][0];
    for (int i = tid; i < R_BLK * HSTR / 2; i += NTHREADS) p[i] = 0u;
    unsigned int* q = (unsigned int*)&x_lds[0][0];
    for (int i = tid; i < 2 * R_BLK * XPAD / 2; i += NTHREADS) q[i] = 0u;
  }

  const bool xa = (tid < R_BLK * S_DIM);
  const int sx_row = tid / 5;
  const int sx_s = tid - 5 * sx_row;
  const float* pobs = obs + (size_t)(row0 + sx_row) * XSTR + sx_s;
  const float* ptgt = target + (size_t)(row0 + sx_row) * XSTR + sx_s;
  float xe = 0.f;

  float pmf[4], kmf[4];
  #pragma unroll
  for (int rt = 0; rt < 4; ++rt) {
    int id = ids[row0 + rt * 16 + lr];
    pmf[rt] = (id == 0) ? 1.0f : 0.0f;
    kmf[rt] = (id == 1) ? 1.0f : 0.0f;
  }

  short8 fh[3][4], fx[3];
  f32x4 brz0, brz1, bnh, bnx;
  setup_weights(eWih, eWhh, ebih, ebhh, fh, fx, brz0, brz1, bnh, bnx, w, lr, lg);

  float h_reg[4][4];
  #pragma unroll
  for (int rt = 0; rt < 4; ++rt)
    #pragma unroll
    for (int i = 0; i < 4; ++i) h_reg[rt][i] = 0.0f;

  __syncthreads();
  if (xa) {
    x_lds[0][sx_row * XPAD + sx_s] = f2bf(pobs[0]);   // v = 0
    xe = pobs[5];                                     // v = 1
  }
  __syncthreads();

  // ---------------- encoder: 64 GRU steps, 2-step unrolled ----------------
  for (int it = 0; it < T_OBS / 2; ++it) {
    const int u = 2 * it;
    // even step (parity 0)
    float xn = 0.f;
    if (xa) {
      int v = u + 2;
      xn = (v < 64) ? pobs[v * 5] : pobs[315];        // v=64 -> obs[63]
    }
    gru_step(&h_lds[0][0], &x_lds[0][0], &h_lds[1][0],
             fh, fx, brz0, brz1, bnh, bnx, h_reg, w, lr, lg);
    if (xa) x_lds[1][sx_row * XPAD + sx_s] = f2bf(xe);
    __syncthreads();
    xe = xn;
    // odd step (parity 1)
    xn = 0.f;
    if (xa) {
      int v = u + 3;
      xn = (v < 64) ? pobs[v * 5] : ptgt[0];          // v=65 -> target[0]
    }
    gru_step(&h_lds[1][0], &x_lds[1][0], &h_lds[0][0],
             fh, fx, brz0, brz1, bnh, bnx, h_reg, w, lr, lg);
    if (xa) x_lds[0][sx_row * XPAD + sx_s] = f2bf(xe);
    __syncthreads();
    xe = xn;
  }

  // ---------------- decoder setup ----------------
  setup_weights(cWih, cWhh, cbih, cbhh, fh, fx, brz0, brz1, bnh, bnx, w, lr, lg);
  short8 fW2[2];
  fW2[0] = load_w(ppW2, A_DIM, 16 * w, H_DIM, A_DIM, 0, lr, lg, 1.0f);
  fW2[1] = load_w(pkW2, A_DIM, 16 * w, H_DIM, A_DIM, 0, lr, lg, 1.0f);
  f32x4 b1v, b2v0, b2v1, hbv;
  {
    const float* b1p = (w & 1) ? pkb1 : ppb1;
    #pragma unroll
    for (int i = 0; i < 4; ++i) {
      b1v[i]  = b1p[4 * lg + i];
      b2v0[i] = ppb2[16 * w + 4 * lg + i];
      b2v1[i] = pkb2[16 * w + 4 * lg + i];
      int s = 4 * lg + i;
      hbv[i] = (s < S_DIM) ? headb[s] : 0.0f;
    }
  }
  for (int f = w; f < 12; f += 8) {
    short8 v;
    if (f < 8) {
      const float* W1 = (f >> 2) ? pkW1 : ppW1;
      v = load_w(W1, H_DIM, 0, A_DIM, H_DIM, f & 3, lr, lg, 1.0f);
    } else {
      v = load_w(headW, H_DIM, 0, S_DIM, H_DIM, f - 8, lr, lg, 1.0f);
    }
    *(short8*)&wd_lds[(f * 64 + lane) * 8] = v;
  }
  __syncthreads();

  // ---------------- decoder: 64 steps (GRU + adapter + head) ----------------
  for (int d = 0; d < F_FUT; ++d) {
    float xn = 0.f;
    if (xa) xn = (d < 63) ? ptgt[(d + 1) * 5] : ptgt[315];
    gru_step(&h_lds[0][0], &x_lds[d & 1][0], &h_lds[1][0],
             fh, fx, brz0, brz1, bnh, bnx, h_reg, w, lr, lg);
    __syncthreads();  // BAR1: h_gru visible

    {   // adapter GEMM1: wave w -> adapter (w&1), row-tile (w>>1)
      const int aa = w & 1;
      const int arow = (w >> 1) * 16 + lr;
      short8 b0 = h_read(&h_lds[1][0], arow, 0, lg);
      f32x4 acc = MFMA(*(const short8*)&wd_lds[((aa * 4 + 0) * 64 + lane) * 8], b0, b1v);
      #pragma unroll
      for (int ks = 1; ks < 4; ++ks) {
        short8 bh = h_read(&h_lds[1][0], arow, ks, lg);
        acc = MFMA(*(const short8*)&wd_lds[((aa * 4 + ks) * 64 + lane) * 8], bh, acc);
      }
      unsigned lo = cvtpk(fmaxf(acc[0], 0.f), fmaxf(acc[1], 0.f));
      unsigned hi = cvtpk(fmaxf(acc[2], 0.f), fmaxf(acc[3], 0.f));
      *(uint2*)&a_lds[(aa * R_BLK + arow) * APAD + 4 * lg] = make_uint2(lo, hi);
    }
    __syncthreads();  // BAR2: a visible

    #pragma unroll
    for (int rt = 0; rt < 4; ++rt) {  // adapter GEMM2 + combine
      const int arow = rt * 16 + lr;
      U8 a0, a1;
      { uint2 t = *(const uint2*)&a_lds[(0 * R_BLK + arow) * APAD + 4 * lg];
        a0.u[0] = t.x; a0.u[1] = t.y; a0.u[2] = 0u; a0.u[3] = 0u; }
      { uint2 t = *(const uint2*)&a_lds[(1 * R_BLK + arow) * APAD + 4 * lg];
        a1.u[0] = t.x; a1.u[1] = t.y; a1.u[2] = 0u; a1.u[3] = 0u; }
      f32x4 d0 = MFMA(fW2[0], a0.v, b2v0);
      f32x4 d1 = MFMA(fW2[1], a1.v, b2v1);
      float hv[4];
      #pragma unroll
      for (int i = 0; i < 4; ++i) {
        float h = h_reg[rt][i] + pmf[rt] * d0[i] + kmf[rt] * d1[i];
        h_reg[rt][i] = h; hv[i] = h;
      }
      h_write(&h_lds[0][0], arow, w, lg, cvtpk(hv[0], hv[1]), cvtpk(hv[2], hv[3]));
    }
    if (xa && d < 63) x_lds[(d + 1) & 1][sx_row * XPAD + sx_s] = f2bf(xe);
    __syncthreads();  // BAR3: h_final visible

    if (w < 4) {  // head: wave w handles row-tile w
      const int arow = w * 16 + lr;
      short8 b0 = h_read(&h_lds[0][0], arow, 0, lg);
      f32x4 acc = MFMA(*(const short8*)&wd_lds[((8 + 0) * 64 + lane) * 8], b0, hbv);
      #pragma unroll
      for (int ks = 1; ks < 4; ++ks) {
        short8 bh = h_read(&h_lds[0][0], arow, ks, lg);
        acc = MFMA(*(const short8*)&wd_lds[((8 + ks) * 64 + lane) * 8], bh, acc);
      }
      float* op = out + (size_t)((row0 + arow) * F_FUT + d) * S_DIM;
      if (lg == 0) { op[0] = acc[0]; op[1] = acc[1]; op[2] = acc[2]; op[3] = acc[3]; }
      else if (lg == 1) { op[4] = acc[0]; }
    }
    xe = xn;
  }
}

extern "C" void kernel_launch(void* const* d_in, const int* in_sizes, int n_in,
                              void* d_out, int out_size, void* d_ws, size_t ws_size,
                              hipStream_t stream) {
  (void)in_sizes; (void)n_in; (void)out_size; (void)d_ws; (void)ws_size;
  const float* obs    = (const float*)d_in[0];
  const float* target = (const float*)d_in[1];
  const int*   ids    = (const int*)d_in[2];
  const float* eWih = (const float*)d_in[3];
  const float* eWhh = (const float*)d_in[4];
  const float* ebih = (const float*)d_in[5];
  const float* ebhh = (const float*)d_in[6];
  const float* cWih = (const float*)d_in[7];
  const float* cWhh = (const float*)d_in[8];
  const float* cbih = (const float*)d_in[9];
  const float* cbhh = (const float*)d_in[10];
  const float* headW = (const float*)d_in[11];
  const float* headb = (const float*)d_in[12];
  const float* ppW1 = (const float*)d_in[13];
  const float* ppb1 = (const float*)d_in[14];
  const float* ppW2 = (const float*)d_in[15];
  const float* ppb2 = (const float*)d_in[16];
  const float* pkW1 = (const float*)d_in[17];
  const float* pkb1 = (const float*)d_in[18];
  const float* pkW2 = (const float*)d_in[19];
  const float* pkb2 = (const float*)d_in[20];

  dim3 grid(B_TOT / R_BLK), block(NTHREADS);
  trace_gru_kernel<<<grid, block, 0, stream>>>(
      obs, target, ids,
      eWih, eWhh, ebih, ebhh,
      cWih, cWhh, cbih, cbhh,
      headW, headb,
      ppW1, ppb1, ppW2, ppb2,
      pkW1, pkb1, pkW2, pkb2,
      (float*)d_out);
}